// Round 3
// baseline (393.717 us; speedup 1.0000x reference)
//
#include <hip/hip_runtime.h>

#define KW 11
#define PAD 5
#define TW 32
#define TH 32
#define IWX 44             // col span incl. halo, padded to even (gc0 = 32*bx-6, even -> 8B aligned)
#define NPAIR 22           // IWX/2 float2-column tasks per row-group
#define S4 45              // float4-plane row stride (ODD -> 13*row mod 32 distinct for 8 rows)
#define SX 45              // sx-plane row stride (ODD -> 2-way banks: free)
#define IMH 512
#define IMW 512
#define NBLK 12288         // 16 x 16 x 48

typedef float f2 __attribute__((ext_vector_type(2)));
typedef float f4 __attribute__((ext_vector_type(4)));

// LDS layout: vv4[row*S4 + col] = (mu1, mu2, q11, q22) float4 (b128 path)
//             vsx[row*SX + col] = x1*x2 moment (b32/b64 path)
// Phase-B b128 bank math (stride 45 f4 = 180 words): 180*row mod 32 = {0,20,8,28,
// 16,4,24,12} distinct for rows 0..7; + 16*(qc&1) -> 8 start banks x 8 lanes
// = 8 words/bank = data-volume minimum.
//
// R2 lesson: WRITE_SIZE ~= img1+img2 size and is INVARIANT under kernel edits
// -> it is harness re-poison dirty-line writeback, not our traffic. Ignore it.
//
// R3: phase A uses float2 column pairs -> 176 tasks = exactly one per thread
// (was 336 -> 2 serial tasks on waves 0-1), 8B loads halve load count and
// double MLP. Phase-A critical path ~halves.

#define PHASE_A(EDGE_)                                                        \
    if (t < NPAIR * 8) {                                                      \
        const int tp = t % NPAIR;                                             \
        const int rg = t / NPAIR;                                             \
        const int c0 = tp * 2;                                                \
        const int gc0 = ix0 + c0;                                             \
        const int r0 = rg * 4;                                                \
        const int gr0 = iy0 + r0;                                             \
        f2 m12a[4] = {{0,0},{0,0},{0,0},{0,0}};                               \
        f2 qqa[4]  = {{0,0},{0,0},{0,0},{0,0}};                               \
        float sxa[4] = {0, 0, 0, 0};                                          \
        f2 m12b[4] = {{0,0},{0,0},{0,0},{0,0}};                               \
        f2 qqb[4]  = {{0,0},{0,0},{0,0},{0,0}};                               \
        float sxb[4] = {0, 0, 0, 0};                                          \
        const bool aok = !(EDGE_) || ((gc0 >= 0) && (gc0 < IMW));             \
        const bool bok = !(EDGE_) || ((gc0 + 1 >= 0) && (gc0 + 1 < IMW));     \
        _Pragma("unroll")                                                     \
        for (int i = 0; i < 14; ++i) {                                        \
            const int gr = gr0 + i;                                           \
            f2 xa, xb; /* xa = (x1,x2) col0; xb = col1 */                     \
            if (EDGE_) {                                                      \
                const bool rok = (gr >= 0) && (gr < IMH);                     \
                const bool o0 = rok && aok;                                   \
                const bool o1 = rok && bok;                                   \
                const size_t p0 = base + (size_t)(o0 ? gr : 0) * IMW          \
                                + (o0 ? gc0 : 0);                             \
                const size_t p1 = base + (size_t)(o1 ? gr : 0) * IMW          \
                                + (o1 ? gc0 + 1 : 0);                         \
                xa.x = o0 ? img1[p0] : 0.f;                                   \
                xa.y = o0 ? img2[p0] : 0.f;                                   \
                xb.x = o1 ? img1[p1] : 0.f;                                   \
                xb.y = o1 ? img2[p1] : 0.f;                                   \
            } else {                                                          \
                const size_t o = base + (size_t)gr * IMW + gc0;               \
                const f2 a1 = *reinterpret_cast<const f2*>(&img1[o]);         \
                const f2 a2 = *reinterpret_cast<const f2*>(&img2[o]);         \
                xa.x = a1.x; xa.y = a2.x;                                     \
                xb.x = a1.y; xb.y = a2.y;                                     \
            }                                                                 \
            const f2 sqa = xa * xa;                                           \
            const f2 sqb = xb * xb;                                           \
            const float sya = xa.x * xa.y;                                    \
            const float syb = xb.x * xb.y;                                    \
            _Pragma("unroll")                                                 \
            for (int k = 0; k < 4; ++k) {                                     \
                const int j = i - k;                                          \
                if (j >= 0 && j < KW) {                                       \
                    const float w = wg[j];                                    \
                    const f2 w2 = {w, w};                                     \
                    m12a[k] += w2 * xa;  qqa[k] += w2 * sqa;                  \
                    sxa[k]  += w * sya;                                       \
                    m12b[k] += w2 * xb;  qqb[k] += w2 * sqb;                  \
                    sxb[k]  += w * syb;                                       \
                }                                                             \
            }                                                                 \
        }                                                                     \
        const int vb = r0 * S4 + c0;                                          \
        _Pragma("unroll")                                                     \
        for (int k = 0; k < 4; ++k) {                                         \
            f4 va, vc;                                                        \
            va.x = m12a[k].x; va.y = m12a[k].y;                               \
            va.z = qqa[k].x;  va.w = qqa[k].y;                                \
            vc.x = m12b[k].x; vc.y = m12b[k].y;                               \
            vc.z = qqb[k].x;  vc.w = qqb[k].y;                                \
            vv4[vb + k * S4]     = va;           /* ds_write_b128 */          \
            vv4[vb + k * S4 + 1] = vc;           /* ds_write_b128 */          \
            f2 sxv; sxv.x = sxa[k]; sxv.y = sxb[k];                           \
            *reinterpret_cast<f2*>(&vsx[(r0 + k) * SX + c0]) = sxv; /* b64 */ \
        }                                                                     \
    }

__global__ __launch_bounds__(256, 5) void ssim_main(
    const float* __restrict__ img1, const float* __restrict__ img2,
    const float* __restrict__ window, float* __restrict__ partial)
{
    __shared__ f4 vv4[TH * S4];          // 23040 B
    __shared__ float vsx[TH * SX];       // 5760 B  -> 28.9 KB total, 5 blocks/CU
    __shared__ float g[KW];
    __shared__ float wsum[4];

    const int t = threadIdx.x;

    // Separable 1D Gaussian = row-sums of the 2D window (columns sum to 1).
    if (t < KW) {
        float s = 0.f;
        for (int j = 0; j < KW; ++j) s += window[(t * KW + j) * 3];
        g[t] = s;
    }
    __syncthreads();

    float wg[KW];
#pragma unroll
    for (int j = 0; j < KW; ++j) wg[j] = g[j];   // broadcast: conflict-free

    const int plane = blockIdx.z;
    const size_t base = (size_t)plane * IMH * IMW;
    const int ix0 = blockIdx.x * TW - PAD - 1;   // even -> float2 loads 8B-aligned
    const int iy0 = blockIdx.y * TH - PAD;

    // ---- Phase A: vertical 11-tap straight from global (lane<->col coalesced).
    // Interior blocks (76.6%) skip all bounds logic (block-uniform branch).
    const bool interior = (ix0 >= 0) && (ix0 + IWX <= IMW) &&
                          (iy0 >= 0) && (iy0 + TH + KW - 1 <= IMH);
    if (interior) {
        PHASE_A(false)
    } else {
        PHASE_A(true)
    }
    __syncthreads();

    // ---- Phase B: horizontal 11-tap + SSIM; 4 adjacent cols per thread.
    // Local col c maps to global col ix0+c; output col X=32bx+qc*4+k needs
    // local cols (X - ix0 - 5 + j) = qc*4+k+1+j, j=0..10 -> base offset +1.
    const float C1v = 0.0001f;
    const float C2v = 0.0009f;
    const int row = t >> 3;                       // 0..31
    const int qc = t & 7;                         // col quad 0..7
    const f4* __restrict__ p4 = &vv4[row * S4 + qc * 4 + 1];
    const float* __restrict__ px = &vsx[row * SX + qc * 4 + 1];
    f2 am12[4] = {{0,0},{0,0},{0,0},{0,0}};
    f2 aqq[4]  = {{0,0},{0,0},{0,0},{0,0}};
    float asx[4] = {0, 0, 0, 0};
#pragma unroll
    for (int cc = 0; cc < 14; ++cc) {
        f4 v = p4[cc];                            // ds_read_b128
        float vx = px[cc];                        // ds_read_b32
        f2 v12 = {v.x, v.y};
        f2 vqq = {v.z, v.w};
#pragma unroll
        for (int k = 0; k < 4; ++k) {
            const int j = cc - k;
            if (j >= 0 && j < KW) {
                float w = wg[j];
                f2 w2 = {w, w};
                am12[k] += w2 * v12;              // v_pk_fma_f32
                aqq[k]  += w2 * vqq;              // v_pk_fma_f32
                asx[k]  += w * vx;
            }
        }
    }
    float lsum = 0.f;
#pragma unroll
    for (int k = 0; k < 4; ++k) {
        float mu1 = am12[k].x, mu2 = am12[k].y;
        float mu1sq = mu1 * mu1, mu2sq = mu2 * mu2, mu12 = mu1 * mu2;
        float sig1 = aqq[k].x - mu1sq;
        float sig2 = aqq[k].y - mu2sq;
        float sig12 = asx[k] - mu12;
        float num = (2.f * mu12 + C1v) * (2.f * sig12 + C2v);
        float den = (mu1sq + mu2sq + C1v) * (sig1 + sig2 + C2v);
        float r = __builtin_amdgcn_rcpf(den);
        r = r * (2.f - den * r);                  // Newton -> ~fp32 exact
        lsum += num * r;
    }

    // ---- Reduction: wave shuffle -> cross-wave LDS -> plain per-block store.
#pragma unroll
    for (int off = 32; off > 0; off >>= 1) lsum += __shfl_down(lsum, off, 64);
    if ((t & 63) == 0) wsum[t >> 6] = lsum;
    __syncthreads();
    if (t == 0) {
        unsigned bid = (blockIdx.z * gridDim.y + blockIdx.y) * gridDim.x
                     + blockIdx.x;
        partial[bid] = wsum[0] + wsum[1] + wsum[2] + wsum[3];
    }
}

__global__ __launch_bounds__(1024) void ssim_reduce(
    const float* __restrict__ partial, float* __restrict__ out, double inv_n)
{
    __shared__ double dsum[16];
    const int t = threadIdx.x;
    double s = 0.0;
    for (int i = t; i < NBLK; i += 1024) s += (double)partial[i];
#pragma unroll
    for (int off = 32; off > 0; off >>= 1) s += __shfl_down(s, off, 64);
    if ((t & 63) == 0) dsum[t >> 6] = s;
    __syncthreads();
    if (t == 0) {
        double tot = 0.0;
#pragma unroll
        for (int w = 0; w < 16; ++w) tot += dsum[w];
        out[0] = (float)(tot * inv_n);
    }
}

extern "C" void kernel_launch(void* const* d_in, const int* in_sizes, int n_in,
                              void* d_out, int out_size, void* d_ws, size_t ws_size,
                              hipStream_t stream) {
    const float* img1   = (const float*)d_in[0];
    const float* img2   = (const float*)d_in[1];
    const float* window = (const float*)d_in[2];
    float* out = (float*)d_out;
    float* partial = (float*)d_ws;               // 12288 floats = 48 KB

    const int nplanes = in_sizes[0] / (IMH * IMW);   // 48
    const long long total = (long long)in_sizes[0];

    dim3 grid(IMW / TW, IMH / TH, nplanes);      // 16 x 16 x 48 = 12288
    ssim_main<<<grid, 256, 0, stream>>>(img1, img2, window, partial);
    ssim_reduce<<<1, 1024, 0, stream>>>(partial, out, 1.0 / (double)total);
}

// Round 5
// 288.636 us; speedup vs baseline: 1.3641x; 1.3641x over previous
//
#include <hip/hip_runtime.h>

#define KW 11
#define PAD 5
#define TW 32
#define TH 32
#define IWX 44             // col span incl. halo, padded to even (gc0 = 32*bx-6, even -> 8B aligned)
#define NPAIR 22           // IWX/2 float2-column tasks per row-group
#define S4 45              // float4-plane row stride (ODD; see bank math below)
#define SX 45              // sx-plane row stride
#define IMH 512
#define IMW 512
#define NBLK 12288         // 16 x 16 x 48

typedef float f2 __attribute__((ext_vector_type(2)));
typedef float f4 __attribute__((ext_vector_type(4)));

// LDS layout: vv4[row*S4 + col] = (mu1, mu2, q11, q22) float4 (b128 path)
//             vsx[row*SX + col] = x1*x2 moment (b32/b64 path)
// Phase-B b128 bank math (stride 45 f4 = 180 words): 180*row mod 32 distinct for
// rows 0..7; + 16*(qc&1) -> 8 distinct 4-word starts -> 8 words/bank = minimum.
//
// R2 lesson: ~100 MB of WRITE_SIZE is harness re-poison dirty-line writeback
// (invariant under kernel edits). Anything ABOVE that is our scratch spill.
// R3 lesson: __launch_bounds__(256,5) forces the <=64-VGPR occupancy tier
// (gfx950 tiers step at 64/128/256 — m69); the paired phase A needs ~80 live
// floats -> compiler spilled (+189 MB writes, VALUBusy 41->16%). LDS (28.9 KB)
// caps residency at 5 blocks/CU anyway, so the 5-waves/SIMD request was
// unreachable: relax to (256,4) -> 128-VGPR budget, 4 blocks/CU, and let all
// 28 phase-A loads stay in flight per thread.

#define PHASE_A(EDGE_)                                                        \
    if (t < NPAIR * 8) {                                                      \
        const int tp = t % NPAIR;                                             \
        const int rg = t / NPAIR;                                             \
        const int c0 = tp * 2;                                                \
        const int gc0 = ix0 + c0;                                             \
        const int r0 = rg * 4;                                                \
        const int gr0 = iy0 + r0;                                             \
        f2 m12a[4] = {{0,0},{0,0},{0,0},{0,0}};                               \
        f2 qqa[4]  = {{0,0},{0,0},{0,0},{0,0}};                               \
        float sxa[4] = {0, 0, 0, 0};                                          \
        f2 m12b[4] = {{0,0},{0,0},{0,0},{0,0}};                               \
        f2 qqb[4]  = {{0,0},{0,0},{0,0},{0,0}};                               \
        float sxb[4] = {0, 0, 0, 0};                                          \
        const bool aok = !(EDGE_) || ((gc0 >= 0) && (gc0 < IMW));             \
        const bool bok = !(EDGE_) || ((gc0 + 1 >= 0) && (gc0 + 1 < IMW));     \
        _Pragma("unroll")                                                     \
        for (int i = 0; i < 14; ++i) {                                        \
            const int gr = gr0 + i;                                           \
            f2 xa, xb; /* xa = (x1,x2) col0; xb = col1 */                     \
            if (EDGE_) {                                                      \
                const bool rok = (gr >= 0) && (gr < IMH);                     \
                const bool o0 = rok && aok;                                   \
                const bool o1 = rok && bok;                                   \
                const size_t p0 = base + (size_t)(o0 ? gr : 0) * IMW          \
                                + (o0 ? gc0 : 0);                             \
                const size_t p1 = base + (size_t)(o1 ? gr : 0) * IMW          \
                                + (o1 ? gc0 + 1 : 0);                         \
                xa.x = o0 ? img1[p0] : 0.f;                                   \
                xa.y = o0 ? img2[p0] : 0.f;                                   \
                xb.x = o1 ? img1[p1] : 0.f;                                   \
                xb.y = o1 ? img2[p1] : 0.f;                                   \
            } else {                                                          \
                const size_t o = base + (size_t)gr * IMW + gc0;               \
                const f2 a1 = *reinterpret_cast<const f2*>(&img1[o]);         \
                const f2 a2 = *reinterpret_cast<const f2*>(&img2[o]);         \
                xa.x = a1.x; xa.y = a2.x;                                     \
                xb.x = a1.y; xb.y = a2.y;                                     \
            }                                                                 \
            const f2 sqa = xa * xa;                                           \
            const f2 sqb = xb * xb;                                           \
            const float sya = xa.x * xa.y;                                    \
            const float syb = xb.x * xb.y;                                    \
            _Pragma("unroll")                                                 \
            for (int k = 0; k < 4; ++k) {                                     \
                const int j = i - k;                                          \
                if (j >= 0 && j < KW) {                                       \
                    const float w = wg[j];                                    \
                    const f2 w2 = {w, w};                                     \
                    m12a[k] += w2 * xa;  qqa[k] += w2 * sqa;                  \
                    sxa[k]  += w * sya;                                       \
                    m12b[k] += w2 * xb;  qqb[k] += w2 * sqb;                  \
                    sxb[k]  += w * syb;                                       \
                }                                                             \
            }                                                                 \
        }                                                                     \
        const int vb = r0 * S4 + c0;                                          \
        _Pragma("unroll")                                                     \
        for (int k = 0; k < 4; ++k) {                                         \
            f4 va, vc;                                                        \
            va.x = m12a[k].x; va.y = m12a[k].y;                               \
            va.z = qqa[k].x;  va.w = qqa[k].y;                                \
            vc.x = m12b[k].x; vc.y = m12b[k].y;                               \
            vc.z = qqb[k].x;  vc.w = qqb[k].y;                                \
            vv4[vb + k * S4]     = va;           /* ds_write_b128 */          \
            vv4[vb + k * S4 + 1] = vc;           /* ds_write_b128 */          \
            f2 sxv; sxv.x = sxa[k]; sxv.y = sxb[k];                           \
            *reinterpret_cast<f2*>(&vsx[(r0 + k) * SX + c0]) = sxv; /* b64 */ \
        }                                                                     \
    }

__global__ __launch_bounds__(256, 4) void ssim_main(
    const float* __restrict__ img1, const float* __restrict__ img2,
    const float* __restrict__ window, float* __restrict__ partial)
{
    __shared__ f4 vv4[TH * S4];          // 23040 B
    __shared__ float vsx[TH * SX];       // 5760 B  -> 28.9 KB total
    __shared__ float g[KW];
    __shared__ float wsum[4];

    const int t = threadIdx.x;

    // Separable 1D Gaussian = row-sums of the 2D window (columns sum to 1).
    if (t < KW) {
        float s = 0.f;
        for (int j = 0; j < KW; ++j) s += window[(t * KW + j) * 3];
        g[t] = s;
    }
    __syncthreads();

    float wg[KW];
#pragma unroll
    for (int j = 0; j < KW; ++j) wg[j] = g[j];   // broadcast: conflict-free

    const int plane = blockIdx.z;
    const size_t base = (size_t)plane * IMH * IMW;
    const int ix0 = blockIdx.x * TW - PAD - 1;   // even -> float2 loads 8B-aligned
    const int iy0 = blockIdx.y * TH - PAD;

    // ---- Phase A: vertical 11-tap straight from global (lane<->col coalesced).
    const bool interior = (ix0 >= 0) && (ix0 + IWX <= IMW) &&
                          (iy0 >= 0) && (iy0 + TH + KW - 1 <= IMH);
    if (interior) {
        PHASE_A(false)
    } else {
        PHASE_A(true)
    }
    __syncthreads();

    // ---- Phase B: horizontal 11-tap + SSIM; 4 adjacent cols per thread.
    // Output col X=32bx+qc*4+k uses local cols qc*4+k+1+j, j=0..10 -> base +1.
    const float C1v = 0.0001f;
    const float C2v = 0.0009f;
    const int row = t >> 3;                       // 0..31
    const int qc = t & 7;                         // col quad 0..7
    const f4* __restrict__ p4 = &vv4[row * S4 + qc * 4 + 1];
    const float* __restrict__ px = &vsx[row * SX + qc * 4 + 1];
    f2 am12[4] = {{0,0},{0,0},{0,0},{0,0}};
    f2 aqq[4]  = {{0,0},{0,0},{0,0},{0,0}};
    float asx[4] = {0, 0, 0, 0};
#pragma unroll
    for (int cc = 0; cc < 14; ++cc) {
        f4 v = p4[cc];                            // ds_read_b128
        float vx = px[cc];                        // ds_read_b32
        f2 v12 = {v.x, v.y};
        f2 vqq = {v.z, v.w};
#pragma unroll
        for (int k = 0; k < 4; ++k) {
            const int j = cc - k;
            if (j >= 0 && j < KW) {
                float w = wg[j];
                f2 w2 = {w, w};
                am12[k] += w2 * v12;              // v_pk_fma_f32
                aqq[k]  += w2 * vqq;              // v_pk_fma_f32
                asx[k]  += w * vx;
            }
        }
    }
    float lsum = 0.f;
#pragma unroll
    for (int k = 0; k < 4; ++k) {
        float mu1 = am12[k].x, mu2 = am12[k].y;
        float mu1sq = mu1 * mu1, mu2sq = mu2 * mu2, mu12 = mu1 * mu2;
        float sig1 = aqq[k].x - mu1sq;
        float sig2 = aqq[k].y - mu2sq;
        float sig12 = asx[k] - mu12;
        float num = (2.f * mu12 + C1v) * (2.f * sig12 + C2v);
        float den = (mu1sq + mu2sq + C1v) * (sig1 + sig2 + C2v);
        float r = __builtin_amdgcn_rcpf(den);
        r = r * (2.f - den * r);                  // Newton -> ~fp32 exact
        lsum += num * r;
    }

    // ---- Reduction: wave shuffle -> cross-wave LDS -> plain per-block store.
#pragma unroll
    for (int off = 32; off > 0; off >>= 1) lsum += __shfl_down(lsum, off, 64);
    if ((t & 63) == 0) wsum[t >> 6] = lsum;
    __syncthreads();
    if (t == 0) {
        unsigned bid = (blockIdx.z * gridDim.y + blockIdx.y) * gridDim.x
                     + blockIdx.x;
        partial[bid] = wsum[0] + wsum[1] + wsum[2] + wsum[3];
    }
}

__global__ __launch_bounds__(1024) void ssim_reduce(
    const float* __restrict__ partial, float* __restrict__ out, double inv_n)
{
    __shared__ double dsum[16];
    const int t = threadIdx.x;
    double s = 0.0;
    for (int i = t; i < NBLK; i += 1024) s += (double)partial[i];
#pragma unroll
    for (int off = 32; off > 0; off >>= 1) s += __shfl_down(s, off, 64);
    if ((t & 63) == 0) dsum[t >> 6] = s;
    __syncthreads();
    if (t == 0) {
        double tot = 0.0;
#pragma unroll
        for (int w = 0; w < 16; ++w) tot += dsum[w];
        out[0] = (float)(tot * inv_n);
    }
}

extern "C" void kernel_launch(void* const* d_in, const int* in_sizes, int n_in,
                              void* d_out, int out_size, void* d_ws, size_t ws_size,
                              hipStream_t stream) {
    const float* img1   = (const float*)d_in[0];
    const float* img2   = (const float*)d_in[1];
    const float* window = (const float*)d_in[2];
    float* out = (float*)d_out;
    float* partial = (float*)d_ws;               // 12288 floats = 48 KB

    const int nplanes = in_sizes[0] / (IMH * IMW);   // 48
    const long long total = (long long)in_sizes[0];

    dim3 grid(IMW / TW, IMH / TH, nplanes);      // 16 x 16 x 48 = 12288
    ssim_main<<<grid, 256, 0, stream>>>(img1, img2, window, partial);
    ssim_reduce<<<1, 1024, 0, stream>>>(partial, out, 1.0 / (double)total);
}

// Round 6
// 173.900 us; speedup vs baseline: 2.2640x; 1.6598x over previous
//
#include <hip/hip_runtime.h>

#define KW 11
#define PAD 5
#define TW 32
#define TH 32
#define IWX 44             // col span incl. halo, padded to even (gc0 = 32*bx-6, even -> 8B aligned)
#define NPAIR 22           // IWX/2 float2-column tasks per row-group
#define S4 45              // float4-plane row stride (ODD; see bank math below)
#define SX 45              // sx-plane row stride
#define IMH 512
#define IMW 512
#define NBLK 12288         // 16 x 16 x 48

typedef float f2 __attribute__((ext_vector_type(2)));
typedef float f4 __attribute__((ext_vector_type(4)));

// LDS layout: vv4[row*S4 + col] = (mu1, mu2, q11, q22) float4 (b128 path)
//             vsx[row*SX + col] = x1*x2 moment (b32/b64 path)
//
// R2 lesson: ~100 MB of WRITE_SIZE is harness re-poison writeback (invariant
// under kernel edits). Anything ABOVE that is our scratch spill.
// R3 lesson: too-tight launch_bounds -> spill (+189 MB WRITE, VALUBusy 16%).
// R5 lesson: block latency == 28 loads x ~900 cyc HBM == ~8.5 us in EVERY
// round -> phase-A loads were SERIALIZED (reg budget 48/64 can't hold 56
// load-data regs; compiler reuses regs -> waitcnt per load group). Fix:
// hoist all loads into distinct regs before first use + (256,2) budget.

#define PHASE_A(EDGE_)                                                        \
    if (t < NPAIR * 8) {                                                      \
        const int tp = t % NPAIR;                                             \
        const int rg = t / NPAIR;                                             \
        const int c0 = tp * 2;                                                \
        const int gc0 = ix0 + c0;                                             \
        const int r0 = rg * 4;                                                \
        const int gr0 = iy0 + r0;                                             \
        f2 a1[14], a2[14];    /* (col0,col1) of img1 / img2 per row */        \
        if (EDGE_) {                                                          \
            const bool aok = (gc0 >= 0) && (gc0 < IMW);                       \
            const bool bok = (gc0 + 1 >= 0) && (gc0 + 1 < IMW);               \
            _Pragma("unroll")                                                 \
            for (int i = 0; i < 14; ++i) {                                    \
                const int gr = gr0 + i;                                       \
                const bool rok = (gr >= 0) && (gr < IMH);                     \
                const bool o0 = rok && aok;                                   \
                const bool o1 = rok && bok;                                   \
                const size_t p0 = base + (size_t)(o0 ? gr : 0) * IMW          \
                                + (o0 ? gc0 : 0);                             \
                const size_t p1 = base + (size_t)(o1 ? gr : 0) * IMW          \
                                + (o1 ? gc0 + 1 : 0);                         \
                a1[i].x = o0 ? img1[p0] : 0.f;                                \
                a1[i].y = o1 ? img1[p1] : 0.f;                                \
                a2[i].x = o0 ? img2[p0] : 0.f;                                \
                a2[i].y = o1 ? img2[p1] : 0.f;                                \
            }                                                                 \
        } else {                                                              \
            /* All 28 8B loads issued back-to-back into distinct regs: */     \
            _Pragma("unroll")                                                 \
            for (int i = 0; i < 14; ++i) {                                    \
                const size_t o = base + (size_t)(gr0 + i) * IMW + gc0;        \
                a1[i] = *reinterpret_cast<const f2*>(&img1[o]);               \
                a2[i] = *reinterpret_cast<const f2*>(&img2[o]);               \
            }                                                                 \
        }                                                                     \
        f2 m12a[4] = {{0,0},{0,0},{0,0},{0,0}};                               \
        f2 qqa[4]  = {{0,0},{0,0},{0,0},{0,0}};                               \
        float sxa[4] = {0, 0, 0, 0};                                          \
        f2 m12b[4] = {{0,0},{0,0},{0,0},{0,0}};                               \
        f2 qqb[4]  = {{0,0},{0,0},{0,0},{0,0}};                               \
        float sxb[4] = {0, 0, 0, 0};                                          \
        _Pragma("unroll")                                                     \
        for (int i = 0; i < 14; ++i) {                                        \
            f2 xa, xb; /* xa = (x1,x2) col0; xb = col1 */                     \
            xa.x = a1[i].x; xa.y = a2[i].x;                                   \
            xb.x = a1[i].y; xb.y = a2[i].y;                                   \
            const f2 sqa = xa * xa;                                           \
            const f2 sqb = xb * xb;                                           \
            const float sya = xa.x * xa.y;                                    \
            const float syb = xb.x * xb.y;                                    \
            _Pragma("unroll")                                                 \
            for (int k = 0; k < 4; ++k) {                                     \
                const int j = i - k;                                          \
                if (j >= 0 && j < KW) {                                       \
                    const float w = wg[j];                                    \
                    const f2 w2 = {w, w};                                     \
                    m12a[k] += w2 * xa;  qqa[k] += w2 * sqa;                  \
                    sxa[k]  += w * sya;                                       \
                    m12b[k] += w2 * xb;  qqb[k] += w2 * sqb;                  \
                    sxb[k]  += w * syb;                                       \
                }                                                             \
            }                                                                 \
        }                                                                     \
        const int vb = r0 * S4 + c0;                                          \
        _Pragma("unroll")                                                     \
        for (int k = 0; k < 4; ++k) {                                         \
            f4 va, vc;                                                        \
            va.x = m12a[k].x; va.y = m12a[k].y;                               \
            va.z = qqa[k].x;  va.w = qqa[k].y;                                \
            vc.x = m12b[k].x; vc.y = m12b[k].y;                               \
            vc.z = qqb[k].x;  vc.w = qqb[k].y;                                \
            vv4[vb + k * S4]     = va;           /* ds_write_b128 */          \
            vv4[vb + k * S4 + 1] = vc;           /* ds_write_b128 */          \
            f2 sxv; sxv.x = sxa[k]; sxv.y = sxb[k];                           \
            *reinterpret_cast<f2*>(&vsx[(r0 + k) * SX + c0]) = sxv; /* b64 */ \
        }                                                                     \
    }

__global__ __launch_bounds__(256, 2) void ssim_main(
    const float* __restrict__ img1, const float* __restrict__ img2,
    const float* __restrict__ window, float* __restrict__ partial)
{
    __shared__ f4 vv4[TH * S4];          // 23040 B
    __shared__ float vsx[TH * SX];       // 5760 B  -> 28.9 KB total
    __shared__ float g[KW];
    __shared__ float wsum[4];

    const int t = threadIdx.x;

    // Separable 1D Gaussian = row-sums of the 2D window (columns sum to 1).
    if (t < KW) {
        float s = 0.f;
        for (int j = 0; j < KW; ++j) s += window[(t * KW + j) * 3];
        g[t] = s;
    }
    __syncthreads();

    float wg[KW];
#pragma unroll
    for (int j = 0; j < KW; ++j) wg[j] = g[j];   // broadcast: conflict-free

    const int plane = blockIdx.z;
    const size_t base = (size_t)plane * IMH * IMW;
    const int ix0 = blockIdx.x * TW - PAD - 1;   // even -> float2 loads 8B-aligned
    const int iy0 = blockIdx.y * TH - PAD;

    // ---- Phase A: vertical 11-tap straight from global (lane<->col coalesced).
    const bool interior = (ix0 >= 0) && (ix0 + IWX <= IMW) &&
                          (iy0 >= 0) && (iy0 + TH + KW - 1 <= IMH);
    if (interior) {
        PHASE_A(false)
    } else {
        PHASE_A(true)
    }
    __syncthreads();

    // ---- Phase B: horizontal 11-tap + SSIM; 4 adjacent cols per thread.
    // Output col X=32bx+qc*4+k uses local cols qc*4+k+1+j, j=0..10 -> base +1.
    const float C1v = 0.0001f;
    const float C2v = 0.0009f;
    const int row = t >> 3;                       // 0..31
    const int qc = t & 7;                         // col quad 0..7
    const f4* __restrict__ p4 = &vv4[row * S4 + qc * 4 + 1];
    const float* __restrict__ px = &vsx[row * SX + qc * 4 + 1];
    // Hoist all 14 b128 + 14 b32 LDS reads -> one lgkmcnt wait, not 14.
    f4 v[14]; float vx[14];
#pragma unroll
    for (int cc = 0; cc < 14; ++cc) { v[cc] = p4[cc]; vx[cc] = px[cc]; }
    f2 am12[4] = {{0,0},{0,0},{0,0},{0,0}};
    f2 aqq[4]  = {{0,0},{0,0},{0,0},{0,0}};
    float asx[4] = {0, 0, 0, 0};
#pragma unroll
    for (int cc = 0; cc < 14; ++cc) {
        f2 v12 = {v[cc].x, v[cc].y};
        f2 vqq = {v[cc].z, v[cc].w};
#pragma unroll
        for (int k = 0; k < 4; ++k) {
            const int j = cc - k;
            if (j >= 0 && j < KW) {
                float w = wg[j];
                f2 w2 = {w, w};
                am12[k] += w2 * v12;              // v_pk_fma_f32
                aqq[k]  += w2 * vqq;              // v_pk_fma_f32
                asx[k]  += w * vx[cc];
            }
        }
    }
    float lsum = 0.f;
#pragma unroll
    for (int k = 0; k < 4; ++k) {
        float mu1 = am12[k].x, mu2 = am12[k].y;
        float mu1sq = mu1 * mu1, mu2sq = mu2 * mu2, mu12 = mu1 * mu2;
        float sig1 = aqq[k].x - mu1sq;
        float sig2 = aqq[k].y - mu2sq;
        float sig12 = asx[k] - mu12;
        float num = (2.f * mu12 + C1v) * (2.f * sig12 + C2v);
        float den = (mu1sq + mu2sq + C1v) * (sig1 + sig2 + C2v);
        float r = __builtin_amdgcn_rcpf(den);
        r = r * (2.f - den * r);                  // Newton -> ~fp32 exact
        lsum += num * r;
    }

    // ---- Reduction: wave shuffle -> cross-wave LDS -> plain per-block store.
#pragma unroll
    for (int off = 32; off > 0; off >>= 1) lsum += __shfl_down(lsum, off, 64);
    if ((t & 63) == 0) wsum[t >> 6] = lsum;
    __syncthreads();
    if (t == 0) {
        unsigned bid = (blockIdx.z * gridDim.y + blockIdx.y) * gridDim.x
                     + blockIdx.x;
        partial[bid] = wsum[0] + wsum[1] + wsum[2] + wsum[3];
    }
}

__global__ __launch_bounds__(1024) void ssim_reduce(
    const float* __restrict__ partial, float* __restrict__ out, double inv_n)
{
    __shared__ double dsum[16];
    const int t = threadIdx.x;
    double s = 0.0;
    for (int i = t; i < NBLK; i += 1024) s += (double)partial[i];
#pragma unroll
    for (int off = 32; off > 0; off >>= 1) s += __shfl_down(s, off, 64);
    if ((t & 63) == 0) dsum[t >> 6] = s;
    __syncthreads();
    if (t == 0) {
        double tot = 0.0;
#pragma unroll
        for (int w = 0; w < 16; ++w) tot += dsum[w];
        out[0] = (float)(tot * inv_n);
    }
}

extern "C" void kernel_launch(void* const* d_in, const int* in_sizes, int n_in,
                              void* d_out, int out_size, void* d_ws, size_t ws_size,
                              hipStream_t stream) {
    const float* img1   = (const float*)d_in[0];
    const float* img2   = (const float*)d_in[1];
    const float* window = (const float*)d_in[2];
    float* out = (float*)d_out;
    float* partial = (float*)d_ws;               // 12288 floats = 48 KB

    const int nplanes = in_sizes[0] / (IMH * IMW);   // 48
    const long long total = (long long)in_sizes[0];

    dim3 grid(IMW / TW, IMH / TH, nplanes);      // 16 x 16 x 48 = 12288
    ssim_main<<<grid, 256, 0, stream>>>(img1, img2, window, partial);
    ssim_reduce<<<1, 1024, 0, stream>>>(partial, out, 1.0 / (double)total);
}